// Round 1
// baseline (124.770 us; speedup 1.0000x reference)
//
#include <hip/hip_runtime.h>
#include <math.h>

#define D_DIM 128
#define K_DIM 64
#define R_DIM 8
#define BT    32   // b-rows per block in main kernel

// Workspace layout (floats):
//   sh2 : [D][K] float2 (s_inv, h=m*s_inv)          offset 0        (16384 floats)
//   w   : [D][K][R]                                  offset 16384    (65536 floats)
//   q   : [K][R]                                     offset 81920    (512 floats)
//   c0  : [K]                                        offset 82432    (64 floats)
#define WS_W_OFF  16384
#define WS_Q_OFF  (16384 + 65536)
#define WS_C0_OFF (16384 + 65536 + 512)

// ---------------------------------------------------------------------------
// Per-k precompute: S_inv, H, Cholesky of capacitance, W = (Sinv*U)·L^-T,
// q_k = W^T m_k, and folded constant c0_k. Grid = K blocks, 128 threads (=D).
// ---------------------------------------------------------------------------
__global__ __launch_bounds__(128) void precomp_kernel(
    const float* __restrict__ m, const float* __restrict__ delta,
    const float* __restrict__ U, const float* __restrict__ lar,
    float* __restrict__ ws) {
  const int k = blockIdx.x;
  const int d = threadIdx.x;  // 0..127

  __shared__ float U_l[D_DIM][R_DIM];
  __shared__ float V_l[D_DIM][R_DIM];
  __shared__ float W_l[D_DIM][R_DIM];
  __shared__ float m_l[D_DIM];
  __shared__ float red[K_DIM];              // Mcap entries (8x8)
  __shared__ float Linv_s[R_DIM][R_DIM];
  __shared__ float redA[D_DIM], redB[D_DIM];

  const float dl   = delta[k * D_DIM + d];
  const float s_inv = expf(-dl);            // 1/exp(delta)
  const float mv   = m[k * D_DIM + d];
  m_l[d] = mv;
  const float* Up = U + (size_t)(k * D_DIM + d) * R_DIM;
#pragma unroll
  for (int r = 0; r < R_DIM; ++r) {
    float u = Up[r];
    U_l[d][r] = u;
    V_l[d][r] = u * s_inv;
  }
  redA[d] = dl;                 // for sum(delta) = logdet of diag part
  redB[d] = mv * mv * s_inv;    // for sum(m^2 * S_inv)
  __syncthreads();

  // Mcap[r][s] = I + sum_d U[d,r]*V[d,s]  (64 entries, one per thread)
  if (d < 64) {
    const int r = d >> 3, s = d & 7;
    float acc = (r == s) ? 1.0f : 0.0f;
    for (int dd = 0; dd < D_DIM; ++dd) acc += U_l[dd][r] * V_l[dd][s];
    red[d] = acc;
  }
  __syncthreads();

  // tree-reduce redA / redB over 128 threads
  for (int off = 64; off > 0; off >>= 1) {
    if (d < off) { redA[d] += redA[d + off]; redB[d] += redB[d + off]; }
    __syncthreads();
  }

  if (d == 0) {
    // 8x8 Cholesky of Mcap (well-conditioned: ~I + O(1e-3))
    float Lm[8][8];
    for (int i = 0; i < 8; ++i)
      for (int j = 0; j <= i; ++j) {
        float sum = red[i * 8 + j];
        for (int p2 = 0; p2 < j; ++p2) sum -= Lm[i][p2] * Lm[j][p2];
        Lm[i][j] = (i == j) ? sqrtf(sum) : sum / Lm[j][j];
      }
    float ld = 0.f;
    for (int i = 0; i < 8; ++i) ld += logf(Lm[i][i]);
    // invert lower-triangular L
    float Li[8][8];
    for (int i = 0; i < 8; ++i)
      for (int j = 0; j < 8; ++j) Li[i][j] = 0.f;
    for (int j = 0; j < 8; ++j) {
      Li[j][j] = 1.0f / Lm[j][j];
      for (int i = j + 1; i < 8; ++i) {
        float sum = 0.f;
        for (int p2 = j; p2 < i; ++p2) sum += Lm[i][p2] * Li[p2][j];
        Li[i][j] = -sum / Lm[i][i];
      }
    }
    for (int i = 0; i < 8; ++i)
      for (int j = 0; j < 8; ++j) Linv_s[i][j] = Li[i][j];

    // folded constant c0_k
    float mean = 0.f;
    for (int j = 0; j < K_DIM; ++j) mean += lar[j];
    mean *= (1.0f / K_DIM);
    const float log_alpha = (lar[k] - mean);     // / eps, eps = 1
    const float logdetS  = redA[0] + 2.0f * ld;  // sum(delta) + 2*sum(log L_ii)
    const float LOG2PI = 1.8378770664093453f;
    const float log_norm = 0.5f * ((float)D_DIM * LOG2PI + logdetS); // log(eps)=0
    ws[WS_C0_OFF + k] = log_alpha - log_norm - 0.5f * redB[0];
  }
  __syncthreads();

  // W[d][r] = sum_{s<=r} V[d][s] * Linv[r][s]   (W = V * L^-T)
  float Wr[R_DIM];
#pragma unroll
  for (int r = 0; r < R_DIM; ++r) {
    float acc = 0.f;
    for (int s2 = 0; s2 <= r; ++s2) acc += V_l[d][s2] * Linv_s[r][s2];
    Wr[r] = acc;
    W_l[d][r] = acc;
  }

  // write k-contiguous tables for coalesced main-kernel reads
  float2* sh2 = (float2*)ws;
  sh2[d * K_DIM + k] = make_float2(s_inv, mv * s_inv);
  float* wout = ws + WS_W_OFF + (size_t)(d * K_DIM + k) * R_DIM;
#pragma unroll
  for (int r = 0; r < R_DIM; ++r) wout[r] = Wr[r];
  __syncthreads();

  // q[k][r] = sum_d W[d][r] * m[d]
  if (d < R_DIM) {
    float acc = 0.f;
    for (int dd = 0; dd < D_DIM; ++dd) acc += W_l[dd][d] * m_l[dd];
    ws[WS_Q_OFF + k * R_DIM + d] = acc;
  }
}

// ---------------------------------------------------------------------------
// Main kernel: one block = BT b-rows, 512 threads = 8 waves.
// Lane = k (64 lanes = K). Each thread register-tiles 4 b-rows.
// logits[b,k] = c0_k + sum_d y*(H - 0.5*Sinv*y) + 0.5*||W^T y - q||^2
// then 64-lane butterfly logsumexp over k.
// ---------------------------------------------------------------------------
__global__ __launch_bounds__(512) void logz_kernel(
    const float* __restrict__ y, const float* __restrict__ ws,
    float* __restrict__ out) {
  const float2* __restrict__ sh2 = (const float2*)ws;
  const float4* __restrict__ w4  = (const float4*)(ws + WS_W_OFF);
  const float*  __restrict__ qp  = ws + WS_Q_OFF;
  const float*  __restrict__ c0  = ws + WS_C0_OFF;

  __shared__ float Yl[BT * D_DIM];

  const int tid = threadIdx.x;
  const int kk  = tid & 63;     // lane = mixture component
  const int bg  = tid >> 6;     // wave id 0..7, owns b-rows bg*4 .. bg*4+3
  const int b0  = blockIdx.x * BT;

  // stage Y tile (BT*128 = 4096 floats = 1024 float4), coalesced
  {
    const float4* ysrc = (const float4*)(y + (size_t)b0 * D_DIM);
    float4* ydst = (float4*)Yl;
    ydst[tid]       = ysrc[tid];
    ydst[tid + 512] = ysrc[tid + 512];
  }
  __syncthreads();

  float g[4] = {0.f, 0.f, 0.f, 0.f};
  float p[4][8];
#pragma unroll
  for (int i = 0; i < 4; ++i)
#pragma unroll
    for (int r = 0; r < 8; ++r) p[i][r] = 0.f;

#pragma unroll 4
  for (int d = 0; d < D_DIM; ++d) {
    const float2 shv = sh2[d * K_DIM + kk];               // (s_inv, h)
    const float4 w0  = w4[(d * K_DIM + kk) * 2];
    const float4 w1  = w4[(d * K_DIM + kk) * 2 + 1];
    const float s05  = -0.5f * shv.x;
#pragma unroll
    for (int i = 0; i < 4; ++i) {
      const float yv = Yl[(bg * 4 + i) * D_DIM + d];      // wave-wide broadcast
      const float t = fmaf(s05, yv, shv.y);               // h - 0.5*s*y
      g[i] = fmaf(yv, t, g[i]);
      p[i][0] = fmaf(yv, w0.x, p[i][0]);
      p[i][1] = fmaf(yv, w0.y, p[i][1]);
      p[i][2] = fmaf(yv, w0.z, p[i][2]);
      p[i][3] = fmaf(yv, w0.w, p[i][3]);
      p[i][4] = fmaf(yv, w1.x, p[i][4]);
      p[i][5] = fmaf(yv, w1.y, p[i][5]);
      p[i][6] = fmaf(yv, w1.z, p[i][6]);
      p[i][7] = fmaf(yv, w1.w, p[i][7]);
    }
  }

  const float4 q0 = ((const float4*)qp)[kk * 2];
  const float4 q1 = ((const float4*)qp)[kk * 2 + 1];
  const float cv  = c0[kk];

#pragma unroll
  for (int i = 0; i < 4; ++i) {
    float d0 = p[i][0] - q0.x, d1 = p[i][1] - q0.y;
    float d2 = p[i][2] - q0.z, d3 = p[i][3] - q0.w;
    float d4 = p[i][4] - q1.x, d5 = p[i][5] - q1.y;
    float d6 = p[i][6] - q1.z, d7 = p[i][7] - q1.w;
    float ss = d0*d0 + d1*d1 + d2*d2 + d3*d3 + d4*d4 + d5*d5 + d6*d6 + d7*d7;
    float val = cv + g[i] + 0.5f * ss;

    // 64-lane butterfly logsumexp over k
    float mx = val;
#pragma unroll
    for (int off = 1; off < 64; off <<= 1)
      mx = fmaxf(mx, __shfl_xor(mx, off, 64));
    float ex = expf(val - mx);
#pragma unroll
    for (int off = 1; off < 64; off <<= 1)
      ex += __shfl_xor(ex, off, 64);
    if (kk == 0) out[b0 + bg * 4 + i] = mx + logf(ex);
  }
}

extern "C" void kernel_launch(void* const* d_in, const int* in_sizes, int n_in,
                              void* d_out, int out_size, void* d_ws, size_t ws_size,
                              hipStream_t stream) {
  const float* y     = (const float*)d_in[0];
  const float* m     = (const float*)d_in[1];
  const float* delta = (const float*)d_in[2];
  const float* U     = (const float*)d_in[3];
  const float* lar   = (const float*)d_in[4];
  float* out = (float*)d_out;
  float* ws  = (float*)d_ws;

  precomp_kernel<<<K_DIM, 128, 0, stream>>>(m, delta, U, lar, ws);
  logz_kernel<<<8192 / BT, 512, 0, stream>>>(y, ws, out);
}